// Round 4
// baseline (460.297 us; speedup 1.0000x reference)
//
#include <hip/hip_runtime.h>

// ---------------------------------------------------------------------------
// Controller: 4-layer LSTM stack + two heads.
// z = [x, h_prev[l], prev_layer]; K=1536 slice for ALL layers is one parallel
// GEMM (gemm_gates); only the K=1024 prev-layer slice is sequential.
//
// R4 changes:
//  * gemm_gates / gemm_heads reverted to the R1-measured forms (420us run).
//  * seq layers rewritten wave-autonomous: conv_wseq pre-converts the
//    prev-layer weight slice to bf16 once; seq_stream = 2048 independent
//    waves, each 16m x 16h x 4 gates via mfma_f32_16x16x32_bf16, 4-deep
//    register prefetch, NO barriers, NO LDS; LSTM cell fused in-register
//    (16x16 C layout puts all 4 gates of one (b,h) in the same lane).
//    XCD map: all 8 blocks of one h-tile land on one XCD -> weight panel
//    fetched into exactly one L2.
//
// ws layout (bytes):
//   A0     @ 0        : bf16 [4][512][1536]   6,291,456
//   G      @ 6291456  : f32  [4][512][4096]  33,554,432  (bias folded)
//   hidden @ 39845888 : bf16 [512][4096]      4,194,304
//   U      @ 44040192 : union { Wseq bf16 [3][4096][1024] 25,165,824  (conv->seq3)
//                               hpart f32 [8][512][768]   12,582,912 (heads->reduce) }
//   total 69,206,016
// ---------------------------------------------------------------------------

typedef short    shortx8  __attribute__((ext_vector_type(8)));
typedef float    floatx4  __attribute__((ext_vector_type(4)));
typedef float    floatx16 __attribute__((ext_vector_type(16)));

__device__ __forceinline__ unsigned int f2bf1(float x) {
  unsigned int u = __float_as_uint(x);
  return (u + 0x7fffu + ((u >> 16) & 1u)) >> 16;   // RNE to bf16 bits
}
__device__ __forceinline__ unsigned int f2bf2(float lo, float hi) {
  return f2bf1(lo) | (f2bf1(hi) << 16);
}
__device__ __forceinline__ float sigm(float x) { return 1.f / (1.f + __expf(-x)); }
__device__ __forceinline__ float tanh_(float x) { return 1.f - 2.f / (__expf(2.f * x) + 1.f); }

// ---------------------------------------------------------------------------
// prep_a0: A0[l][b][0:1536] = bf16(x[b] ++ h_prev[l][b]).  grid (384,4) x 256
// ---------------------------------------------------------------------------
__global__ __launch_bounds__(256) void prep_a0(const float* __restrict__ x,
                                               const float* __restrict__ hp,
                                               unsigned short* __restrict__ A0) {
  const int l   = blockIdx.y;
  const int idx = blockIdx.x * 256 + threadIdx.x;   // < 512*192
  const int b   = idx / 192;
  const int kk  = (idx - b * 192) * 8;
  float v[8];
  if (kk < 512) {
    const float* s = x + (size_t)b * 512 + kk;
#pragma unroll
    for (int i = 0; i < 8; ++i) v[i] = s[i];
  } else {
    const float* s = hp + ((size_t)l * 512 + b) * 1024 + (kk - 512);
#pragma unroll
    for (int i = 0; i < 8; ++i) v[i] = s[i];
  }
  uint4 o;
  o.x = f2bf2(v[0], v[1]); o.y = f2bf2(v[2], v[3]);
  o.z = f2bf2(v[4], v[5]); o.w = f2bf2(v[6], v[7]);
  *(uint4*)(A0 + ((size_t)l * 512 + b) * 1536 + kk) = o;
}

// ---------------------------------------------------------------------------
// conv_wseq: Wseq[(l-1)][n][k] = bf16(Wg[l][n][1536+k]), l=1..3. grid 6144x256
// ---------------------------------------------------------------------------
__global__ __launch_bounds__(256) void conv_wseq(const float* __restrict__ Wg,
                                                 unsigned short* __restrict__ Wseq) {
  const int idx = blockIdx.x * 256 + threadIdx.x;   // < 12288*128
  const int row = idx >> 7;          // (l-1)*4096 + n
  const int k0  = (idx & 127) * 8;
  const int l   = (row >> 12) + 1;   // 1..3
  const int n   = row & 4095;
  const float* s = Wg + (size_t)l * 4096 * 2560 + (size_t)n * 2560 + 1536 + k0;
  const float4 v0 = *(const float4*)(s);
  const float4 v1 = *(const float4*)(s + 4);
  uint4 o;
  o.x = f2bf2(v0.x, v0.y); o.y = f2bf2(v0.z, v0.w);
  o.z = f2bf2(v1.x, v1.y); o.w = f2bf2(v1.z, v1.w);
  *(uint4*)(Wseq + (size_t)row * 1024 + k0) = o;
}

// ---------------------------------------------------------------------------
// gemm_gates (R1-measured form): BM=BN=128 BK=64, 256 thr, dbuf LDS (64KB,
// 2 blocks/CU), 1-deep register prefetch. grid (4,32,4), XCD swizzle.
// ---------------------------------------------------------------------------
__global__ __launch_bounds__(256, 2) void gemm_gates(
    const unsigned short* __restrict__ A0, const float* __restrict__ Wg,
    const float* __restrict__ bg, float* __restrict__ G) {
  __shared__ __align__(16) unsigned short As[2][128 * 64];
  __shared__ __align__(16) unsigned short Bs[2][128 * 64];
  const int tid = threadIdx.x, lane = tid & 63, wave = tid >> 6;
  const int raw   = blockIdx.x + 4 * (blockIdx.y + 32 * blockIdx.z); // 0..511
  const int xcd   = raw & 7, slot = raw >> 3;                        // slot 0..63
  const int nl    = (slot >> 2) * 8 + xcd;                           // 0..127
  const int mbase = (slot & 3) * 128;
  const int nbase = (nl & 31) * 128;
  const int l     = nl >> 5;
  const unsigned short* Ab = A0 + ((size_t)l * 512 + mbase) * 1536;
  const float*          Bb = Wg + (size_t)l * 4096 * 2560 + (size_t)nbase * 2560;
  const int arow = wave * 8 + (lane >> 3);
  const int akg  = lane & 7;

  uint4  apf[4];
  float4 bpf[8];
  auto loadT = [&](int kt) {
    const int kg = kt * 64;
#pragma unroll
    for (int r = 0; r < 4; ++r)
      apf[r] = *(const uint4*)(Ab + (size_t)(arow + r * 32) * 1536 + kg + akg * 8);
#pragma unroll
    for (int j = 0; j < 8; ++j) {
      const int idx = j * 256 + tid;
      bpf[j] = *(const float4*)(Bb + (size_t)(idx >> 4) * 2560 + kg + (idx & 15) * 4);
    }
  };
  auto storeT = [&](int buf) {
#pragma unroll
    for (int r = 0; r < 4; ++r) {
      const int row = arow + r * 32;
      *(uint4*)(&As[buf][row * 64 + ((akg ^ (row & 7)) * 8)]) = apf[r];
    }
#pragma unroll
    for (int j = 0; j < 8; ++j) {
      const int idx = j * 256 + tid;
      const int n = idx >> 4, kc = (idx & 15) * 4;
      uint2 pk;
      pk.x = f2bf2(bpf[j].x, bpf[j].y);
      pk.y = f2bf2(bpf[j].z, bpf[j].w);
      *(uint2*)(&Bs[buf][n * 64 + (((kc >> 3) ^ (n & 7)) * 8) + (kc & 4)]) = pk;
    }
  };

  floatx16 acc[2][2];
#pragma unroll
  for (int a = 0; a < 2; ++a)
#pragma unroll
    for (int b2 = 0; b2 < 2; ++b2)
#pragma unroll
      for (int r = 0; r < 16; ++r) acc[a][b2][r] = 0.f;

  const int wm = (wave >> 1) * 64, wn = (wave & 1) * 64;
  loadT(0);
  storeT(0);
  __syncthreads();
  for (int kt = 0; kt < 24; ++kt) {
    if (kt + 1 < 24) loadT(kt + 1);
    const int cb = kt & 1;
#pragma unroll
    for (int ks = 0; ks < 4; ++ks) {
      const int gb = ks * 2 + (lane >> 5);
      shortx8 af[2], bfv[2];
#pragma unroll
      for (int sm = 0; sm < 2; ++sm) {
        const int row = wm + sm * 32 + (lane & 31);
        af[sm] = *(const shortx8*)(&As[cb][row * 64 + ((gb ^ (row & 7)) * 8)]);
      }
#pragma unroll
      for (int sn = 0; sn < 2; ++sn) {
        const int row = wn + sn * 32 + (lane & 31);
        bfv[sn] = *(const shortx8*)(&Bs[cb][row * 64 + ((gb ^ (row & 7)) * 8)]);
      }
#pragma unroll
      for (int sm = 0; sm < 2; ++sm)
#pragma unroll
        for (int sn = 0; sn < 2; ++sn)
          acc[sm][sn] = __builtin_amdgcn_mfma_f32_32x32x16_bf16(
              af[sm], bfv[sn], acc[sm][sn], 0, 0, 0);
    }
    if (kt + 1 < 24) storeT((kt + 1) & 1);
    __syncthreads();
  }

  const float* bgl = bg + (size_t)l * 4096;
  float* Gl = G + ((size_t)l * 512 + mbase) * 4096;
#pragma unroll
  for (int sm = 0; sm < 2; ++sm)
#pragma unroll
    for (int sn = 0; sn < 2; ++sn) {
      const int col = nbase + wn + sn * 32 + (lane & 31);
      const float bias = bgl[col];
#pragma unroll
      for (int r = 0; r < 16; ++r) {
        const int row = wm + sm * 32 + ((r & 3) + 8 * (r >> 2) + 4 * (lane >> 5));
        Gl[(size_t)row * 4096 + col] = acc[sm][sn][r] + bias;
      }
    }
}

// ---------------------------------------------------------------------------
// cell0: layer 0 has zero prev-layer input -> pure pointwise on G[0].
// ---------------------------------------------------------------------------
__global__ __launch_bounds__(256) void cell0(const float* __restrict__ G,
                                             const float* __restrict__ cp_l,
                                             unsigned short* __restrict__ hidden) {
  const int idx = (blockIdx.x * 256 + threadIdx.x) * 4;
  const int b = idx >> 10, h = idx & 1023;
  const float* g0 = G + (size_t)b * 4096;
  const float4 vi = *(const float4*)(g0 + h);
  const float4 vf = *(const float4*)(g0 + 1024 + h);
  const float4 vo = *(const float4*)(g0 + 2048 + h);
  const float4 vs = *(const float4*)(g0 + 3072 + h);
  const float4 cp = *(const float4*)(cp_l + (size_t)b * 1024 + h);
  const float gi[4] = {vi.x, vi.y, vi.z, vi.w};
  const float gf[4] = {vf.x, vf.y, vf.z, vf.w};
  const float go[4] = {vo.x, vo.y, vo.z, vo.w};
  const float gs[4] = {vs.x, vs.y, vs.z, vs.w};
  const float cc[4] = {cp.x, cp.y, cp.z, cp.w};
  float hn[4];
#pragma unroll
  for (int j = 0; j < 4; ++j) {
    const float c = sigm(gf[j]) * cc[j] + sigm(gi[j]) * tanh_(gs[j]);
    hn[j] = sigm(go[j]) * tanh_(c);
  }
  uint2 o;
  o.x = f2bf2(hn[0], hn[1]);
  o.y = f2bf2(hn[2], hn[3]);
  *(uint2*)(hidden + (size_t)b * 4096 + h) = o;
}

// ---------------------------------------------------------------------------
// seq_stream: wave-autonomous seq-layer GEMM + fused LSTM cell.
// 512 blocks x 256 thr = 2048 waves; wave = one 16m x 16h tile x 4 gates.
// Per k-step (K=32): 1 A-frag + 4 B-frags (16B each) + 4 MFMA 16x16x32.
// 4-deep named-register prefetch, no barriers, no LDS.
// k-mapping k = 8*(lane>>4)+e applied identically to A and B (contraction-
// invariant permutation). C layout: col=lane&15, row=(lane>>4)*4+reg ->
// all 4 gates of one (b,h) in the same lane -> in-register cell.
// XCD map: bid=(x + 8m + 64t): ht=x*8+t -> all 8 m-group blocks of one
// h-tile share XCD x -> each weight panel lives in exactly one L2.
// ---------------------------------------------------------------------------
__global__ __launch_bounds__(256) void seq_stream(
    const unsigned short* __restrict__ hidden_ro,
    const unsigned short* __restrict__ Wseq,
    const float* __restrict__ G, const float* __restrict__ c_prev,
    unsigned short* __restrict__ hidden_w, int l) {
  const int tid = threadIdx.x, lane = tid & 63, wv = tid >> 6;
  const int bid = blockIdx.x;            // 0..511
  const int x   = bid & 7;               // xcd
  const int mg  = (bid >> 3) & 7;        // m-group
  const int t   = bid >> 6;              // 0..7
  const int ht  = x * 8 + t;             // 0..63
  const int mt  = mg * 4 + wv;           // 0..31
  const int mb  = mt * 16, h0 = ht * 16;
  const int lrow = lane & 15, lg = lane >> 4;

  const unsigned short* Ab = hidden_ro + (size_t)(mb + lrow) * 4096
                             + (size_t)(l - 1) * 1024 + lg * 8;
  const unsigned short* Bb = Wseq + (size_t)(l - 1) * 4194304
                             + (size_t)(h0 + lrow) * 1024 + lg * 8;

  // epilogue operands issued up front (independent of the K loop)
  const int brow = mb + lg * 4;
  const int hg   = h0 + lrow;
  float gvv[4][4];   // [gate][r]
  float cold[4];
#pragma unroll
  for (int r = 0; r < 4; ++r) {
    const float* Gb = G + ((size_t)l * 512 + brow + r) * 4096 + hg;
#pragma unroll
    for (int g = 0; g < 4; ++g) gvv[g][r] = Gb[g * 1024];
    cold[r] = c_prev[((size_t)l * 512 + brow + r) * 1024 + hg];
  }

  floatx4 acc0, acc1, acc2, acc3;
#pragma unroll
  for (int r = 0; r < 4; ++r) { acc0[r] = 0.f; acc1[r] = 0.f; acc2[r] = 0.f; acc3[r] = 0.f; }

  shortx8 a0, a1, a2, a3;
  shortx8 b00, b01, b02, b03;   // set0, gates 0..3
  shortx8 b10, b11, b12, b13;
  shortx8 b20, b21, b22, b23;
  shortx8 b30, b31, b32, b33;

#define LD_SET(ai, b0_, b1_, b2_, b3_, kt)                                   \
  {                                                                          \
    const int ko = (kt) * 32;                                                \
    ai  = *(const shortx8*)(Ab + ko);                                        \
    b0_ = *(const shortx8*)(Bb + ko);                                        \
    b1_ = *(const shortx8*)(Bb + 1048576 + ko);                              \
    b2_ = *(const shortx8*)(Bb + 2097152 + ko);                              \
    b3_ = *(const shortx8*)(Bb + 3145728 + ko);                              \
  }
#define C_SET(ai, b0_, b1_, b2_, b3_)                                        \
  {                                                                          \
    acc0 = __builtin_amdgcn_mfma_f32_16x16x32_bf16(ai, b0_, acc0, 0, 0, 0);  \
    acc1 = __builtin_amdgcn_mfma_f32_16x16x32_bf16(ai, b1_, acc1, 0, 0, 0);  \
    acc2 = __builtin_amdgcn_mfma_f32_16x16x32_bf16(ai, b2_, acc2, 0, 0, 0);  \
    acc3 = __builtin_amdgcn_mfma_f32_16x16x32_bf16(ai, b3_, acc3, 0, 0, 0);  \
  }

  LD_SET(a0, b00, b01, b02, b03, 0)
  LD_SET(a1, b10, b11, b12, b13, 1)
  LD_SET(a2, b20, b21, b22, b23, 2)
  LD_SET(a3, b30, b31, b32, b33, 3)
#pragma unroll 1
  for (int kt4 = 0; kt4 < 8; ++kt4) {
    const int kt = kt4 * 4;
    C_SET(a0, b00, b01, b02, b03)
    if (kt + 4 < 32) LD_SET(a0, b00, b01, b02, b03, kt + 4)
    C_SET(a1, b10, b11, b12, b13)
    if (kt + 5 < 32) LD_SET(a1, b10, b11, b12, b13, kt + 5)
    C_SET(a2, b20, b21, b22, b23)
    if (kt + 6 < 32) LD_SET(a2, b20, b21, b22, b23, kt + 6)
    C_SET(a3, b30, b31, b32, b33)
    if (kt + 7 < 32) LD_SET(a3, b30, b31, b32, b33, kt + 7)
  }
#undef LD_SET
#undef C_SET

  // fused LSTM cell, fully in-register
#pragma unroll
  for (int r = 0; r < 4; ++r) {
    const float gi = acc0[r] + gvv[0][r];
    const float gf = acc1[r] + gvv[1][r];
    const float go = acc2[r] + gvv[2][r];
    const float gs = acc3[r] + gvv[3][r];
    const float c  = sigm(gf) * cold[r] + sigm(gi) * tanh_(gs);
    const float hn = sigm(go) * tanh_(c);
    hidden_w[(size_t)(brow + r) * 4096 + l * 1024 + hg] = (unsigned short)f2bf1(hn);
  }
}

// ---------------------------------------------------------------------------
// gemm_heads (R1-measured form): split-K, BM=BN=128 BK=64, dbuf, 1-deep
// prefetch, grid (8 ksplit, 6 n, 4 m), XCD swizzle.
// ---------------------------------------------------------------------------
__global__ __launch_bounds__(256) void gemm_heads(
    const unsigned short* __restrict__ A, const float* __restrict__ Wy,
    const float* __restrict__ WE, float* __restrict__ Cp) {
  __shared__ __align__(16) unsigned short As[2][128 * 64];
  __shared__ __align__(16) unsigned short Bs[2][128 * 64];
  const int tid = threadIdx.x, lane = tid & 63, wave = tid >> 6;
  const int rawb = blockIdx.x + 8 * (blockIdx.y + 6 * blockIdx.z); // 0..191
  const int xcd  = rawb & 7, slot = rawb >> 3;  // slot 0..23
  const int pair = (slot >> 2) * 8 + xcd;       // 0..47 = (nt, ksplit)
  const int mbase  = (slot & 3) * 128;
  const int ksplit = pair & 7;
  const int nt     = pair >> 3;                 // 0..5
  const int nbase  = nt * 128;
  const float* Bb = (nt < 4) ? (Wy + (size_t)nbase * 4096)
                             : (WE + (size_t)(nbase - 512) * 4096);
  const int k0 = ksplit * 512;
  const unsigned short* Ab = A + (size_t)mbase * 4096;
  const int arow = wave * 8 + (lane >> 3);
  const int akg  = lane & 7;

  uint4  apf[4];
  float4 bpf[8];
  auto loadT = [&](int kt) {
    const int kg = k0 + kt * 64;
#pragma unroll
    for (int r = 0; r < 4; ++r)
      apf[r] = *(const uint4*)(Ab + (size_t)(arow + r * 32) * 4096 + kg + akg * 8);
#pragma unroll
    for (int j = 0; j < 8; ++j) {
      const int idx = j * 256 + tid;
      bpf[j] = *(const float4*)(Bb + (size_t)(idx >> 4) * 4096 + kg + (idx & 15) * 4);
    }
  };
  auto storeT = [&](int buf) {
#pragma unroll
    for (int r = 0; r < 4; ++r) {
      const int row = arow + r * 32;
      *(uint4*)(&As[buf][row * 64 + ((akg ^ (row & 7)) * 8)]) = apf[r];
    }
#pragma unroll
    for (int j = 0; j < 8; ++j) {
      const int idx = j * 256 + tid;
      const int n = idx >> 4, kc = (idx & 15) * 4;
      uint2 pk;
      pk.x = f2bf2(bpf[j].x, bpf[j].y);
      pk.y = f2bf2(bpf[j].z, bpf[j].w);
      *(uint2*)(&Bs[buf][n * 64 + (((kc >> 3) ^ (n & 7)) * 8) + (kc & 4)]) = pk;
    }
  };

  floatx16 acc[2][2];
#pragma unroll
  for (int a = 0; a < 2; ++a)
#pragma unroll
    for (int b2 = 0; b2 < 2; ++b2)
#pragma unroll
      for (int r = 0; r < 16; ++r) acc[a][b2][r] = 0.f;
  const int wm = (wave >> 1) * 64, wn = (wave & 1) * 64;

  loadT(0);
  storeT(0);
  __syncthreads();
  for (int kt = 0; kt < 8; ++kt) {
    if (kt + 1 < 8) loadT(kt + 1);
    const int cb = kt & 1;
#pragma unroll
    for (int ks = 0; ks < 4; ++ks) {
      const int gb = ks * 2 + (lane >> 5);
      shortx8 af[2], bfv[2];
#pragma unroll
      for (int sm = 0; sm < 2; ++sm) {
        const int row = wm + sm * 32 + (lane & 31);
        af[sm] = *(const shortx8*)(&As[cb][row * 64 + ((gb ^ (row & 7)) * 8)]);
      }
#pragma unroll
      for (int sn = 0; sn < 2; ++sn) {
        const int row = wn + sn * 32 + (lane & 31);
        bfv[sn] = *(const shortx8*)(&Bs[cb][row * 64 + ((gb ^ (row & 7)) * 8)]);
      }
#pragma unroll
      for (int sm = 0; sm < 2; ++sm)
#pragma unroll
        for (int sn = 0; sn < 2; ++sn)
          acc[sm][sn] = __builtin_amdgcn_mfma_f32_32x32x16_bf16(
              af[sm], bfv[sn], acc[sm][sn], 0, 0, 0);
    }
    if (kt + 1 < 8) storeT((kt + 1) & 1);
    __syncthreads();
  }

  float* Co = Cp + (size_t)ksplit * 512 * 768;
#pragma unroll
  for (int sm = 0; sm < 2; ++sm)
#pragma unroll
    for (int sn = 0; sn < 2; ++sn) {
      const int col = nbase + wn + sn * 32 + (lane & 31);
#pragma unroll
      for (int r = 0; r < 16; ++r) {
        const int row = mbase + wm + sm * 32 +
                        ((r & 3) + 8 * (r >> 2) + 4 * (lane >> 5));
        Co[(size_t)row * 768 + col] = acc[sm][sn][r];
      }
    }
}

// ---------------------------------------------------------------------------
// head_reduce: sum 8 k-split partials + bias -> d_out.  grid (3,512) x 256
// ---------------------------------------------------------------------------
__global__ __launch_bounds__(256) void head_reduce(
    const float* __restrict__ hp, const float* __restrict__ b_y,
    const float* __restrict__ b_E, float* __restrict__ out) {
  const int n = blockIdx.x * 256 + threadIdx.x;  // 0..767
  const int b = blockIdx.y;
  float s = 0.f;
#pragma unroll
  for (int ks = 0; ks < 8; ++ks)
    s += hp[(size_t)ks * 512 * 768 + (size_t)b * 768 + n];
  if (n < 512)
    out[(size_t)b * 512 + n] = s + b_y[n];
  else
    out[(size_t)512 * 512 + (size_t)b * 256 + (n - 512)] = s + b_E[n - 512];
}

// ---------------------------------------------------------------------------
extern "C" void kernel_launch(void* const* d_in, const int* in_sizes, int n_in,
                              void* d_out, int out_size, void* d_ws, size_t ws_size,
                              hipStream_t stream) {
  const float* x      = (const float*)d_in[0];
  const float* h_prev = (const float*)d_in[1];
  const float* c_prev = (const float*)d_in[2];
  const float* Wg     = (const float*)d_in[3];
  const float* bg     = (const float*)d_in[4];
  const float* W_y    = (const float*)d_in[5];
  const float* b_y    = (const float*)d_in[6];
  const float* W_E    = (const float*)d_in[7];
  const float* b_E    = (const float*)d_in[8];

  char* ws = (char*)d_ws;
  unsigned short* A0     = (unsigned short*)(ws + 0);
  float*          G      = (float*)(ws + 6291456);
  unsigned short* hidden = (unsigned short*)(ws + 39845888);
  unsigned short* Wseq   = (unsigned short*)(ws + 44040192);  // dead after seq3
  float*          hpart  = (float*)(ws + 44040192);           // live heads->reduce

  conv_wseq<<<dim3(6144), 256, 0, stream>>>(Wg, Wseq);
  prep_a0<<<dim3(384, 4), 256, 0, stream>>>(x, h_prev, A0);
  gemm_gates<<<dim3(4, 32, 4), 256, 0, stream>>>(A0, Wg, bg, G);
  cell0<<<512, 256, 0, stream>>>(G, c_prev, hidden);
  for (int l = 1; l < 4; ++l)
    seq_stream<<<dim3(512), 256, 0, stream>>>(hidden, Wseq, G, c_prev,
                                              hidden, l);
  gemm_heads<<<dim3(8, 6, 4), 256, 0, stream>>>(hidden, W_y, W_E, hpart);
  head_reduce<<<dim3(3, 512), 256, 0, stream>>>(hpart, b_y, b_E, (float*)d_out);
}